// Round 8
// baseline (476.575 us; speedup 1.0000x reference)
//
#include <hip/hip_runtime.h>
#include <hip/hip_bf16.h>

#define GN 100000   // nodes
#define GE 3200000  // edges
#define GH 128      // feature/hidden width
#define GA 1024     // actions
#define GB 256      // graphs

#define NBUK 391    // buckets of 256 nodes (ceil(GN/256))
#define B1BLK 5120  // edges per k_bin1 block
#define NBIN1 625   // k_bin1 blocks: 625 * 5120 = GE exactly

// round-to-nearest-even fp32 -> bf16 (as ushort)
__device__ __forceinline__ unsigned int f2bf(float f) {
    unsigned int u = __float_as_uint(f);
    return (u + 0x7fffu + ((u >> 16) & 1u)) >> 16;
}
__device__ __forceinline__ float bflo(unsigned int u) { return __uint_as_float(u << 16); }
__device__ __forceinline__ float bfhi(unsigned int u) { return __uint_as_float(u & 0xffff0000u); }

// ---------------- CSR build: coarse bin (LDS-staged coalesced) + in-bucket sort ----

__global__ __launch_bounds__(256) void k_hist_coarse(const int* __restrict__ dst,
                                                     int* __restrict__ cnt) {
    __shared__ int h[NBUK];
    int t = threadIdx.x;
    for (int i = t; i < NBUK; i += 256) h[i] = 0;
    __syncthreads();
    int beg = blockIdx.x * 3125;  // 1024 blocks * 3125 = GE exactly
    for (int e = beg + t; e < beg + 3125; e += 256)
        atomicAdd(&h[dst[e] >> 8], 1);
    __syncthreads();
    for (int i = t; i < NBUK; i += 256) {
        int c = h[i];
        if (c) atomicAdd(&cnt[i], c);
    }
}

// parallel exclusive scan of 391 counts (padded to 512), 2 elements/thread
__global__ __launch_bounds__(256) void k_scan_coarse(const int* __restrict__ cnt,
                                                     int* __restrict__ gcur,
                                                     int* __restrict__ cbase,
                                                     int* __restrict__ offsets) {
    __shared__ int wsc[4];
    int t = threadIdx.x;
    int i0 = 2 * t, i1 = 2 * t + 1;
    int v0 = (i0 < NBUK) ? cnt[i0] : 0;
    int v1 = (i1 < NBUK) ? cnt[i1] : 0;
    int s = v0 + v1;
    int lane = t & 63, w = t >> 6;
    int x = s;
#pragma unroll
    for (int off = 1; off < 64; off <<= 1) {
        int y = __shfl_up(x, off);
        if (lane >= off) x += y;
    }
    if (lane == 63) wsc[w] = x;
    __syncthreads();
    int wo = 0;
#pragma unroll
    for (int i = 0; i < 4; i++)
        if (i < w) wo += wsc[i];
    int excl = wo + x - s;
    if (i0 < NBUK) { cbase[i0] = excl; gcur[i0] = excl; }
    if (i1 < NBUK) { cbase[i1] = excl + v0; gcur[i1] = excl + v0; }
    if (t == 0) { cbase[NBUK] = GE; offsets[GN] = GE; }
}

// block-local LDS counting sort into 391 buckets, then coalesced run writes
__global__ __launch_bounds__(256) void k_bin1(const int* __restrict__ src,
                                              const int* __restrict__ dst,
                                              int* __restrict__ gcur,
                                              unsigned int* __restrict__ binned) {
    __shared__ int hist[512], lstart[512];
    __shared__ int curl[NBUK], gbase[NBUK];
    __shared__ unsigned int srec[B1BLK];
    __shared__ unsigned short sbuk[B1BLK];
    __shared__ int wsc[4];
    int t = threadIdx.x;
    hist[t] = 0; hist[t + 256] = 0;
    __syncthreads();
    int beg = blockIdx.x * B1BLK;
    unsigned int rec[20]; int bukv[20];
#pragma unroll
    for (int k = 0; k < 20; k++) {          // 256 * 20 = 5120 = B1BLK exactly
        int e = beg + t + k * 256;
        int d = dst[e];
        rec[k] = (unsigned int)src[e] | ((unsigned int)(d & 255) << 17);
        bukv[k] = d >> 8;
        atomicAdd(&hist[bukv[k]], 1);
    }
    __syncthreads();
    // parallel scan of 512 bucket counts, 2/thread
    int v0 = hist[2 * t], v1 = hist[2 * t + 1];
    int s = v0 + v1;
    int lane = t & 63, w = t >> 6;
    int x = s;
#pragma unroll
    for (int off = 1; off < 64; off <<= 1) {
        int y = __shfl_up(x, off);
        if (lane >= off) x += y;
    }
    if (lane == 63) wsc[w] = x;
    __syncthreads();
    int wo = 0;
#pragma unroll
    for (int i = 0; i < 4; i++)
        if (i < w) wo += wsc[i];
    int excl = wo + x - s;
    lstart[2 * t] = excl;
    lstart[2 * t + 1] = excl + v0;
    __syncthreads();
    for (int i = t; i < NBUK; i += 256) {
        curl[i] = lstart[i];
        int c = hist[i];
        gbase[i] = c ? atomicAdd(&gcur[i], c) : 0;
    }
    __syncthreads();
#pragma unroll
    for (int k = 0; k < 20; k++) {
        int p = atomicAdd(&curl[bukv[k]], 1);
        srec[p] = rec[k];
        sbuk[p] = (unsigned short)bukv[k];
    }
    __syncthreads();
    // coalesced run writes: consecutive threads -> consecutive slots -> consecutive addrs
    for (int i = t; i < B1BLK; i += 256) {
        int b = sbuk[i];
        binned[gbase[b] + (i - lstart[b])] = srec[i];
    }
}

// one 256-thread block per bucket: sort to node granularity -> CSR + dinv
__global__ __launch_bounds__(256) void k_sort2(const unsigned int* __restrict__ binned,
                                               const int* __restrict__ cbase,
                                               int* __restrict__ csr_src,
                                               int* __restrict__ offsets,
                                               float* __restrict__ dinv) {
    int b = blockIdx.x, t = threadIdx.x;
    __shared__ int hist[256], cur[256], wsum[4];
    hist[t] = 0;
    __syncthreads();
    int rbase = cbase[b], rend = cbase[b + 1];
    for (int e = rbase + t; e < rend; e += 256)
        atomicAdd(&hist[(binned[e] >> 17) & 255], 1);
    __syncthreads();
    int h = hist[t];
    int lane = t & 63, w = t >> 6;
    int x = h;
#pragma unroll
    for (int off = 1; off < 64; off <<= 1) {
        int y = __shfl_up(x, off);
        if (lane >= off) x += y;
    }
    if (lane == 63) wsum[w] = x;
    __syncthreads();
    int wo = 0;
#pragma unroll
    for (int i = 0; i < 4; i++)
        if (i < w) wo += wsum[i];
    int excl = wo + x - h;  // exclusive prefix within bucket
    int node = (b << 8) + t;
    if (node < GN) {
        offsets[node] = rbase + excl;
        dinv[node] = rsqrtf((float)(h + 1));  // +1 self-loop
    }
    cur[t] = excl;
    __syncthreads();
    for (int e = rbase + t; e < rend; e += 256) {
        unsigned int v = binned[e];
        int dl = (v >> 17) & 255;
        int p = atomicAdd(&cur[dl], 1);
        csr_src[rbase + p] = (int)(v & 0x1FFFF);
    }
}

// one wave per node: bitonic-sort the neighbor list ascending (perf-only:
// in-phase waves then sweep src 0->GN together => gather band fits per-XCD L2)
__global__ __launch_bounds__(256) void k_sortnbr(const int* __restrict__ offsets,
                                                 int* __restrict__ csr_src) {
    int node = blockIdx.x * 4 + (threadIdx.x >> 6);
    if (node >= GN) return;
    int lane = threadIdx.x & 63;
    int beg = offsets[node];
    int n = offsets[node + 1] - beg;
    if (n < 2 || n > 64) return;  // >64: skip (rare; sorting is perf-only)
    int v = (lane < n) ? csr_src[beg + lane] : 0x7FFFFFFF;
#pragma unroll
    for (int k = 2; k <= 64; k <<= 1) {
#pragma unroll
        for (int j = k >> 1; j > 0; j >>= 1) {
            int other = __shfl_xor(v, j);
            bool lower = (lane & j) == 0;
            bool asc = (lane & k) == 0;
            v = (lower == asc) ? min(v, other) : max(v, other);
        }
    }
    if (lane < n) csr_src[beg + lane] = v;
}

// ---------------- GEMM (fp32 A): C[row] = bf16(dinv[row] * (A[row] @ W))
// 64-row tiles, 4 rows/thread (VALU-bound: 4 LDS scalar reads feed 32 FMAs)
__global__ __launch_bounds__(256) void k_gemm_f32(const float* __restrict__ A,
                                                  const float* __restrict__ W,
                                                  const float* __restrict__ dinv,
                                                  unsigned int* __restrict__ C) {
    __shared__ float Ws[64][128];
    __shared__ float As[64][68];
    int t = threadIdx.x;
    int ty = t >> 4, tx = t & 15;
    int row0 = blockIdx.x * 64;

    float4 accA[4] = {{0,0,0,0},{0,0,0,0},{0,0,0,0},{0,0,0,0}};
    float4 accB[4] = {{0,0,0,0},{0,0,0,0},{0,0,0,0},{0,0,0,0}};

    for (int kb = 0; kb < 128; kb += 64) {
#pragma unroll
        for (int i = 0; i < 8; i++) {
            int q = t + 256 * i;
            int kr = q >> 5;
            int c4 = (q & 31) << 2;
            *(float4*)&Ws[kr][c4] = *(const float4*)&W[(kb + kr) * 128 + c4];
        }
#pragma unroll
        for (int i = 0; i < 4; i++) {
            int q = t + 256 * i;
            int ar = q >> 4;
            int c4 = (q & 15) << 2;
            int row = row0 + ar; if (row >= GN) row = GN - 1;
            *(float4*)&As[ar][c4] = *(const float4*)&A[(size_t)row * 128 + kb + c4];
        }
        __syncthreads();
#pragma unroll 4
        for (int k = 0; k < 64; k++) {
            float4 b0 = *(float4*)&Ws[k][tx * 4];
            float4 b1 = *(float4*)&Ws[k][64 + tx * 4];
#pragma unroll
            for (int r = 0; r < 4; r++) {
                float a = As[ty * 4 + r][k];
                accA[r].x = fmaf(a, b0.x, accA[r].x); accA[r].y = fmaf(a, b0.y, accA[r].y);
                accA[r].z = fmaf(a, b0.z, accA[r].z); accA[r].w = fmaf(a, b0.w, accA[r].w);
                accB[r].x = fmaf(a, b1.x, accB[r].x); accB[r].y = fmaf(a, b1.y, accB[r].y);
                accB[r].z = fmaf(a, b1.z, accB[r].z); accB[r].w = fmaf(a, b1.w, accB[r].w);
            }
        }
        __syncthreads();
    }
#pragma unroll
    for (int r = 0; r < 4; r++) {
        int row = row0 + ty * 4 + r;
        if (row >= GN) continue;
        float dv = dinv[row];
        float4 oA = accA[r], oB = accB[r];
        uint2 pA, pB;
        pA.x = f2bf(oA.x * dv) | (f2bf(oA.y * dv) << 16);
        pA.y = f2bf(oA.z * dv) | (f2bf(oA.w * dv) << 16);
        pB.x = f2bf(oB.x * dv) | (f2bf(oB.y * dv) << 16);
        pB.y = f2bf(oB.z * dv) | (f2bf(oB.w * dv) << 16);
        *(uint2*)&C[(size_t)row * 64 + tx * 2] = pA;
        *(uint2*)&C[(size_t)row * 64 + 32 + tx * 2] = pB;
    }
}

// ---------------- GEMM (bf16 A): same tiling, A rows are 64 packed uints
__global__ __launch_bounds__(256) void k_gemm_bf16(const unsigned int* __restrict__ A,
                                                   const float* __restrict__ W,
                                                   const float* __restrict__ dinv,
                                                   unsigned int* __restrict__ C) {
    __shared__ float Ws[64][128];
    __shared__ float As[64][68];
    int t = threadIdx.x;
    int ty = t >> 4, tx = t & 15;
    int row0 = blockIdx.x * 64;

    float4 accA[4] = {{0,0,0,0},{0,0,0,0},{0,0,0,0},{0,0,0,0}};
    float4 accB[4] = {{0,0,0,0},{0,0,0,0},{0,0,0,0},{0,0,0,0}};

    for (int kb = 0; kb < 128; kb += 64) {
#pragma unroll
        for (int i = 0; i < 8; i++) {
            int q = t + 256 * i;
            int kr = q >> 5;
            int c4 = (q & 31) << 2;
            *(float4*)&Ws[kr][c4] = *(const float4*)&W[(kb + kr) * 128 + c4];
        }
        {
            int ar = t >> 2;              // 64 rows, 4 threads/row
            int cu = (t & 3) * 8;         // 8 uints per thread (32 uints/row-kblock)
            int row = row0 + ar; if (row >= GN) row = GN - 1;
            uint4 av0 = *(const uint4*)&A[(size_t)row * 64 + (kb >> 1) + cu];
            uint4 av1 = *(const uint4*)&A[(size_t)row * 64 + (kb >> 1) + cu + 4];
            unsigned int uu[8] = {av0.x, av0.y, av0.z, av0.w, av1.x, av1.y, av1.z, av1.w};
#pragma unroll
            for (int i = 0; i < 8; i++) {
                As[ar][(cu + i) * 2 + 0] = bflo(uu[i]);
                As[ar][(cu + i) * 2 + 1] = bfhi(uu[i]);
            }
        }
        __syncthreads();
#pragma unroll 4
        for (int k = 0; k < 64; k++) {
            float4 b0 = *(float4*)&Ws[k][tx * 4];
            float4 b1 = *(float4*)&Ws[k][64 + tx * 4];
#pragma unroll
            for (int r = 0; r < 4; r++) {
                float a = As[ty * 4 + r][k];
                accA[r].x = fmaf(a, b0.x, accA[r].x); accA[r].y = fmaf(a, b0.y, accA[r].y);
                accA[r].z = fmaf(a, b0.z, accA[r].z); accA[r].w = fmaf(a, b0.w, accA[r].w);
                accB[r].x = fmaf(a, b1.x, accB[r].x); accB[r].y = fmaf(a, b1.y, accB[r].y);
                accB[r].z = fmaf(a, b1.z, accB[r].z); accB[r].w = fmaf(a, b1.w, accB[r].w);
            }
        }
        __syncthreads();
    }
#pragma unroll
    for (int r = 0; r < 4; r++) {
        int row = row0 + ty * 4 + r;
        if (row >= GN) continue;
        float dv = dinv[row];
        float4 oA = accA[r], oB = accB[r];
        uint2 pA, pB;
        pA.x = f2bf(oA.x * dv) | (f2bf(oA.y * dv) << 16);
        pA.y = f2bf(oA.z * dv) | (f2bf(oA.w * dv) << 16);
        pB.x = f2bf(oB.x * dv) | (f2bf(oB.y * dv) << 16);
        pB.y = f2bf(oB.z * dv) | (f2bf(oB.w * dv) << 16);
        *(uint2*)&C[(size_t)row * 64 + tx * 2] = pA;
        *(uint2*)&C[(size_t)row * 64 + 32 + tx * 2] = pB;
    }
}

// ------------- aggregation: h[v] = relu(dinv[v]*(sum ts[src] + ts[v]) + b), bf16 out
__global__ __launch_bounds__(256) void k_aggregate(const unsigned int* __restrict__ ts,
                                                   const int* __restrict__ offsets,
                                                   const int* __restrict__ csr_src,
                                                   const float* __restrict__ dinv,
                                                   const float* __restrict__ bias,
                                                   unsigned int* __restrict__ out) {
    int node = blockIdx.x * 4 + (threadIdx.x >> 6);
    if (node >= GN) return;
    int lane = threadIdx.x & 63;
    int beg = offsets[node];
    int end = offsets[node + 1];
    float di = dinv[node];
    float ax = 0.f, ay = 0.f;
    for (int base = beg; base < end; base += 64) {
        int n = end - base; if (n > 64) n = 64;
        int myidx = (lane < n) ? csr_src[base + lane] : 0;  // coalesced index load
        int k = 0;
        for (; k + 16 <= n; k += 16) {
            unsigned int u[16];
#pragma unroll
            for (int q = 0; q < 16; q++) {
                int s = __shfl(myidx, k + q);
                u[q] = ts[s * 64 + lane];
            }
#pragma unroll
            for (int q = 0; q < 16; q++) { ax += bflo(u[q]); ay += bfhi(u[q]); }
        }
        for (; k + 4 <= n; k += 4) {
            unsigned int u[4];
#pragma unroll
            for (int q = 0; q < 4; q++) {
                int s = __shfl(myidx, k + q);
                u[q] = ts[s * 64 + lane];
            }
#pragma unroll
            for (int q = 0; q < 4; q++) { ax += bflo(u[q]); ay += bfhi(u[q]); }
        }
        for (; k < n; k++) {
            int s = __shfl(myidx, k);
            unsigned int u = ts[s * 64 + lane];
            ax += bflo(u); ay += bfhi(u);
        }
    }
    unsigned int su = ts[(size_t)node * 64 + lane];  // self-loop (pre-scaled)
    float bx = bias[lane * 2 + 0], by = bias[lane * 2 + 1];
    float ox = fmaxf(fmaf(di, ax + bflo(su), bx), 0.f);
    float oy = fmaxf(fmaf(di, ay + bfhi(su), by), 0.f);
    out[(size_t)node * 64 + lane] = f2bf(ox) | (f2bf(oy) << 16);
}

// ------------- mean pool per graph (batch sorted), bf16 h input -------------
__global__ __launch_bounds__(256) void k_pool(const unsigned int* __restrict__ h,
                                              const int* __restrict__ batch,
                                              float* __restrict__ pooled) {
    int g = blockIdx.x;
    int t = threadIdx.x;
    int f = t & 63, part = t >> 6;  // f: uint col, part: 4-way row split
    int lo = 0, hi = GN;
    while (lo < hi) { int m = (lo + hi) >> 1; if (batch[m] < g) lo = m + 1; else hi = m; }
    int start = lo;
    hi = GN;
    while (lo < hi) { int m = (lo + hi) >> 1; if (batch[m] <= g) lo = m + 1; else hi = m; }
    int end = lo;
    float ax = 0.f, ay = 0.f;
    for (int i = start + part; i < end; i += 4) {
        unsigned int u = h[(size_t)i * 64 + f];
        ax += bflo(u); ay += bfhi(u);
    }
    __shared__ float redx[256], redy[256];
    redx[t] = ax; redy[t] = ay;
    __syncthreads();
    if (part == 0) {
        float sx = redx[f] + redx[f + 64] + redx[f + 128] + redx[f + 192];
        float sy = redy[f] + redy[f + 64] + redy[f + 128] + redy[f + 192];
        float inv = 1.0f / fmaxf((float)(end - start), 1.0f);
        pooled[g * 128 + 2 * f + 0] = sx * inv;
        pooled[g * 128 + 2 * f + 1] = sy * inv;
    }
}

// ------------- value head -------------
__global__ void k_value(const float* __restrict__ pooled, const float* __restrict__ Wv,
                        const float* __restrict__ bv, float* __restrict__ out) {
    int g = threadIdx.x;
    const float4* p4 = (const float4*)(pooled + g * 128);
    const float4* w4 = (const float4*)Wv;
    float s = 0.f;
#pragma unroll 8
    for (int i = 0; i < 32; i++) {
        float4 a = p4[i], b = w4[i];
        s += a.x * b.x + a.y * b.y + a.z * b.z + a.w * b.w;
    }
    out[g] = tanhf(s + bv[0]);
}

// ------------- policy head -------------
__global__ __launch_bounds__(256) void k_policy(const float* __restrict__ pooled,
                                                const float* __restrict__ Wp,
                                                const float* __restrict__ bp,
                                                float* __restrict__ out) {
    int g = blockIdx.x;
    int t = threadIdx.x;
    __shared__ float pr[128];
    __shared__ float red[256];
    if (t < 128) pr[t] = pooled[g * 128 + t];
    __syncthreads();
    float acc0 = bp[t + 0], acc1 = bp[t + 256], acc2 = bp[t + 512], acc3 = bp[t + 768];
    for (int k = 0; k < 128; k++) {
        float pv = pr[k];
        const float* wr = Wp + (size_t)k * 1024;
        acc0 = fmaf(pv, wr[t + 0],   acc0);
        acc1 = fmaf(pv, wr[t + 256], acc1);
        acc2 = fmaf(pv, wr[t + 512], acc2);
        acc3 = fmaf(pv, wr[t + 768], acc3);
    }
    float m = fmaxf(fmaxf(acc0, acc1), fmaxf(acc2, acc3));
    red[t] = m;
    __syncthreads();
    for (int off = 128; off > 0; off >>= 1) {
        if (t < off) red[t] = fmaxf(red[t], red[t + off]);
        __syncthreads();
    }
    float mx = red[0];
    __syncthreads();
    float e0 = __expf(acc0 - mx), e1 = __expf(acc1 - mx);
    float e2 = __expf(acc2 - mx), e3 = __expf(acc3 - mx);
    red[t] = (e0 + e1) + (e2 + e3);
    __syncthreads();
    for (int off = 128; off > 0; off >>= 1) {
        if (t < off) red[t] += red[t + off];
        __syncthreads();
    }
    float inv = 1.0f / red[0];
    out[(size_t)g * 1024 + t + 0]   = e0 * inv;
    out[(size_t)g * 1024 + t + 256] = e1 * inv;
    out[(size_t)g * 1024 + t + 512] = e2 * inv;
    out[(size_t)g * 1024 + t + 768] = e3 * inv;
}

extern "C" void kernel_launch(void* const* d_in, const int* in_sizes, int n_in,
                              void* d_out, int out_size, void* d_ws, size_t ws_size,
                              hipStream_t stream) {
    const float* x    = (const float*)d_in[0];
    const int*   ei   = (const int*)d_in[1];
    const int*   srcA = ei;        // edge_index[0]
    const int*   dstA = ei + GE;   // edge_index[1]
    const int*   batch = (const int*)d_in[2];
    const float* W1 = (const float*)d_in[3];
    const float* b1 = (const float*)d_in[4];
    const float* W2 = (const float*)d_in[5];
    const float* b2 = (const float*)d_in[6];
    const float* Wv = (const float*)d_in[7];
    const float* bv = (const float*)d_in[8];
    const float* Wp = (const float*)d_in[9];
    const float* bp = (const float*)d_in[10];
    float* out = (float*)d_out;

    char* ws = (char*)d_ws;
    unsigned int* bufH = (unsigned int*)ws;  ws += (size_t)GN * 64 * 4;  // 25.6 MB bf16 h
    unsigned int* ts_bf = (unsigned int*)ws; ws += (size_t)GN * 64 * 4;  // 25.6 MB bf16 ts
    float* pooled = (float*)ws;      ws += (size_t)GB * 128 * 4;
    float* dinv = (float*)ws;        ws += (size_t)100352 * 4;
    int*   csr_src = (int*)ws;       ws += (size_t)GE * 4;               // 12.8 MB
    int*   offsets = (int*)ws;       ws += (size_t)100352 * 4;
    int*   coarse_cnt = (int*)ws;    ws += 512 * 4;
    int*   gcur = (int*)ws;          ws += 512 * 4;
    int*   cbase = (int*)ws;         ws += 512 * 4;
    unsigned int* binned = ts_bf;    // alias: consumed by k_sort2 before gemm1 writes ts

    // --- CSR build ---
    hipMemsetAsync(coarse_cnt, 0, NBUK * 4, stream);
    k_hist_coarse<<<1024, 256, 0, stream>>>(dstA, coarse_cnt);
    k_scan_coarse<<<1, 256, 0, stream>>>(coarse_cnt, gcur, cbase, offsets);
    k_bin1<<<NBIN1, 256, 0, stream>>>(srcA, dstA, gcur, binned);
    k_sort2<<<NBUK, 256, 0, stream>>>(binned, cbase, csr_src, offsets, dinv);
    k_sortnbr<<<GN / 4, 256, 0, stream>>>(offsets, csr_src);

    // --- layer 1: ts = bf16(dinv .* (x @ W1)); h1 = relu(dinv*(gather + self) + b1) ---
    k_gemm_f32<<<(GN + 63) / 64, 256, 0, stream>>>(x, W1, dinv, ts_bf);
    k_aggregate<<<GN / 4, 256, 0, stream>>>(ts_bf, offsets, csr_src, dinv, b1, bufH);

    // --- layer 2 ---
    k_gemm_bf16<<<(GN + 63) / 64, 256, 0, stream>>>(bufH, W2, dinv, ts_bf);
    k_aggregate<<<GN / 4, 256, 0, stream>>>(ts_bf, offsets, csr_src, dinv, b2, bufH);

    // --- pool + heads ---
    k_pool<<<GB, 256, 0, stream>>>(bufH, batch, pooled);
    k_value<<<1, 256, 0, stream>>>(pooled, Wv, bv, out);
    k_policy<<<GB, 256, 0, stream>>>(pooled, Wp, bp, out + GB);
}

// Round 9
// 474.291 us; speedup vs baseline: 1.0048x; 1.0048x over previous
//
#include <hip/hip_runtime.h>
#include <hip/hip_bf16.h>

#define GN 100000   // nodes
#define GE 3200000  // edges
#define GH 128      // feature/hidden width
#define GA 1024     // actions
#define GB 256      // graphs

#define NBUK 391    // buckets of 256 nodes (ceil(GN/256))
#define B1BLK 5120  // edges per k_bin1 block
#define NBIN1 625   // k_bin1 blocks: 625 * 5120 = GE exactly

// round-to-nearest-even fp32 -> bf16 (as ushort)
__device__ __forceinline__ unsigned int f2bf(float f) {
    unsigned int u = __float_as_uint(f);
    return (u + 0x7fffu + ((u >> 16) & 1u)) >> 16;
}
__device__ __forceinline__ float bflo(unsigned int u) { return __uint_as_float(u << 16); }
__device__ __forceinline__ float bfhi(unsigned int u) { return __uint_as_float(u & 0xffff0000u); }

// ---------------- CSR build: coarse bin (LDS-staged coalesced) + in-bucket sort ----

__global__ __launch_bounds__(256) void k_hist_coarse(const int* __restrict__ dst,
                                                     int* __restrict__ cnt) {
    __shared__ int h[NBUK];
    int t = threadIdx.x;
    for (int i = t; i < NBUK; i += 256) h[i] = 0;
    __syncthreads();
    int beg = blockIdx.x * 3125;  // 1024 blocks * 3125 = GE exactly
    for (int e = beg + t; e < beg + 3125; e += 256)
        atomicAdd(&h[dst[e] >> 8], 1);
    __syncthreads();
    for (int i = t; i < NBUK; i += 256) {
        int c = h[i];
        if (c) atomicAdd(&cnt[i], c);
    }
}

// parallel exclusive scan of 391 counts (padded to 512), 2 elements/thread
__global__ __launch_bounds__(256) void k_scan_coarse(const int* __restrict__ cnt,
                                                     int* __restrict__ gcur,
                                                     int* __restrict__ cbase,
                                                     int* __restrict__ offsets) {
    __shared__ int wsc[4];
    int t = threadIdx.x;
    int i0 = 2 * t, i1 = 2 * t + 1;
    int v0 = (i0 < NBUK) ? cnt[i0] : 0;
    int v1 = (i1 < NBUK) ? cnt[i1] : 0;
    int s = v0 + v1;
    int lane = t & 63, w = t >> 6;
    int x = s;
#pragma unroll
    for (int off = 1; off < 64; off <<= 1) {
        int y = __shfl_up(x, off);
        if (lane >= off) x += y;
    }
    if (lane == 63) wsc[w] = x;
    __syncthreads();
    int wo = 0;
#pragma unroll
    for (int i = 0; i < 4; i++)
        if (i < w) wo += wsc[i];
    int excl = wo + x - s;
    if (i0 < NBUK) { cbase[i0] = excl; gcur[i0] = excl; }
    if (i1 < NBUK) { cbase[i1] = excl + v0; gcur[i1] = excl + v0; }
    if (t == 0) { cbase[NBUK] = GE; offsets[GN] = GE; }
}

// block-local LDS counting sort into 391 buckets, then coalesced run writes
__global__ __launch_bounds__(256) void k_bin1(const int* __restrict__ src,
                                              const int* __restrict__ dst,
                                              int* __restrict__ gcur,
                                              unsigned int* __restrict__ binned) {
    __shared__ int hist[512], lstart[512];
    __shared__ int curl[NBUK], gbase[NBUK];
    __shared__ unsigned int srec[B1BLK];
    __shared__ unsigned short sbuk[B1BLK];
    __shared__ int wsc[4];
    int t = threadIdx.x;
    hist[t] = 0; hist[t + 256] = 0;
    __syncthreads();
    int beg = blockIdx.x * B1BLK;
    unsigned int rec[20]; int bukv[20];
#pragma unroll
    for (int k = 0; k < 20; k++) {          // 256 * 20 = 5120 = B1BLK exactly
        int e = beg + t + k * 256;
        int d = dst[e];
        rec[k] = (unsigned int)src[e] | ((unsigned int)(d & 255) << 17);
        bukv[k] = d >> 8;
        atomicAdd(&hist[bukv[k]], 1);
    }
    __syncthreads();
    // parallel scan of 512 bucket counts, 2/thread
    int v0 = hist[2 * t], v1 = hist[2 * t + 1];
    int s = v0 + v1;
    int lane = t & 63, w = t >> 6;
    int x = s;
#pragma unroll
    for (int off = 1; off < 64; off <<= 1) {
        int y = __shfl_up(x, off);
        if (lane >= off) x += y;
    }
    if (lane == 63) wsc[w] = x;
    __syncthreads();
    int wo = 0;
#pragma unroll
    for (int i = 0; i < 4; i++)
        if (i < w) wo += wsc[i];
    int excl = wo + x - s;
    lstart[2 * t] = excl;
    lstart[2 * t + 1] = excl + v0;
    __syncthreads();
    for (int i = t; i < NBUK; i += 256) {
        curl[i] = lstart[i];
        int c = hist[i];
        gbase[i] = c ? atomicAdd(&gcur[i], c) : 0;
    }
    __syncthreads();
#pragma unroll
    for (int k = 0; k < 20; k++) {
        int p = atomicAdd(&curl[bukv[k]], 1);
        srec[p] = rec[k];
        sbuk[p] = (unsigned short)bukv[k];
    }
    __syncthreads();
    // coalesced run writes: consecutive threads -> consecutive slots -> consecutive addrs
    for (int i = t; i < B1BLK; i += 256) {
        int b = sbuk[i];
        binned[gbase[b] + (i - lstart[b])] = srec[i];
    }
}

// one 256-thread block per bucket: sort to node granularity -> CSR + dinv
__global__ __launch_bounds__(256) void k_sort2(const unsigned int* __restrict__ binned,
                                               const int* __restrict__ cbase,
                                               int* __restrict__ csr_src,
                                               int* __restrict__ offsets,
                                               float* __restrict__ dinv) {
    int b = blockIdx.x, t = threadIdx.x;
    __shared__ int hist[256], cur[256], wsum[4];
    hist[t] = 0;
    __syncthreads();
    int rbase = cbase[b], rend = cbase[b + 1];
    for (int e = rbase + t; e < rend; e += 256)
        atomicAdd(&hist[(binned[e] >> 17) & 255], 1);
    __syncthreads();
    int h = hist[t];
    int lane = t & 63, w = t >> 6;
    int x = h;
#pragma unroll
    for (int off = 1; off < 64; off <<= 1) {
        int y = __shfl_up(x, off);
        if (lane >= off) x += y;
    }
    if (lane == 63) wsum[w] = x;
    __syncthreads();
    int wo = 0;
#pragma unroll
    for (int i = 0; i < 4; i++)
        if (i < w) wo += wsum[i];
    int excl = wo + x - h;  // exclusive prefix within bucket
    int node = (b << 8) + t;
    if (node < GN) {
        offsets[node] = rbase + excl;
        dinv[node] = rsqrtf((float)(h + 1));  // +1 self-loop
    }
    cur[t] = excl;
    __syncthreads();
    for (int e = rbase + t; e < rend; e += 256) {
        unsigned int v = binned[e];
        int dl = (v >> 17) & 255;
        int p = atomicAdd(&cur[dl], 1);
        csr_src[rbase + p] = (int)(v & 0x1FFFF);
    }
}

// ---------------- GEMM (fp32 A): C[row] = bf16(dinv[row] * (A[row] @ W))
// 64-row tiles, 4 rows/thread (VALU-bound: 4 LDS scalar reads feed 32 FMAs)
__global__ __launch_bounds__(256) void k_gemm_f32(const float* __restrict__ A,
                                                  const float* __restrict__ W,
                                                  const float* __restrict__ dinv,
                                                  unsigned int* __restrict__ C) {
    __shared__ float Ws[64][128];
    __shared__ float As[64][68];
    int t = threadIdx.x;
    int ty = t >> 4, tx = t & 15;
    int row0 = blockIdx.x * 64;

    float4 accA[4] = {{0,0,0,0},{0,0,0,0},{0,0,0,0},{0,0,0,0}};
    float4 accB[4] = {{0,0,0,0},{0,0,0,0},{0,0,0,0},{0,0,0,0}};

    for (int kb = 0; kb < 128; kb += 64) {
#pragma unroll
        for (int i = 0; i < 8; i++) {
            int q = t + 256 * i;
            int kr = q >> 5;
            int c4 = (q & 31) << 2;
            *(float4*)&Ws[kr][c4] = *(const float4*)&W[(kb + kr) * 128 + c4];
        }
#pragma unroll
        for (int i = 0; i < 4; i++) {
            int q = t + 256 * i;
            int ar = q >> 4;
            int c4 = (q & 15) << 2;
            int row = row0 + ar; if (row >= GN) row = GN - 1;
            *(float4*)&As[ar][c4] = *(const float4*)&A[(size_t)row * 128 + kb + c4];
        }
        __syncthreads();
#pragma unroll 4
        for (int k = 0; k < 64; k++) {
            float4 b0 = *(float4*)&Ws[k][tx * 4];
            float4 b1 = *(float4*)&Ws[k][64 + tx * 4];
#pragma unroll
            for (int r = 0; r < 4; r++) {
                float a = As[ty * 4 + r][k];
                accA[r].x = fmaf(a, b0.x, accA[r].x); accA[r].y = fmaf(a, b0.y, accA[r].y);
                accA[r].z = fmaf(a, b0.z, accA[r].z); accA[r].w = fmaf(a, b0.w, accA[r].w);
                accB[r].x = fmaf(a, b1.x, accB[r].x); accB[r].y = fmaf(a, b1.y, accB[r].y);
                accB[r].z = fmaf(a, b1.z, accB[r].z); accB[r].w = fmaf(a, b1.w, accB[r].w);
            }
        }
        __syncthreads();
    }
#pragma unroll
    for (int r = 0; r < 4; r++) {
        int row = row0 + ty * 4 + r;
        if (row >= GN) continue;
        float dv = dinv[row];
        float4 oA = accA[r], oB = accB[r];
        uint2 pA, pB;
        pA.x = f2bf(oA.x * dv) | (f2bf(oA.y * dv) << 16);
        pA.y = f2bf(oA.z * dv) | (f2bf(oA.w * dv) << 16);
        pB.x = f2bf(oB.x * dv) | (f2bf(oB.y * dv) << 16);
        pB.y = f2bf(oB.z * dv) | (f2bf(oB.w * dv) << 16);
        *(uint2*)&C[(size_t)row * 64 + tx * 2] = pA;
        *(uint2*)&C[(size_t)row * 64 + 32 + tx * 2] = pB;
    }
}

// ---------------- GEMM (bf16 A): same tiling, A rows are 64 packed uints
__global__ __launch_bounds__(256) void k_gemm_bf16(const unsigned int* __restrict__ A,
                                                   const float* __restrict__ W,
                                                   const float* __restrict__ dinv,
                                                   unsigned int* __restrict__ C) {
    __shared__ float Ws[64][128];
    __shared__ float As[64][68];
    int t = threadIdx.x;
    int ty = t >> 4, tx = t & 15;
    int row0 = blockIdx.x * 64;

    float4 accA[4] = {{0,0,0,0},{0,0,0,0},{0,0,0,0},{0,0,0,0}};
    float4 accB[4] = {{0,0,0,0},{0,0,0,0},{0,0,0,0},{0,0,0,0}};

    for (int kb = 0; kb < 128; kb += 64) {
#pragma unroll
        for (int i = 0; i < 8; i++) {
            int q = t + 256 * i;
            int kr = q >> 5;
            int c4 = (q & 31) << 2;
            *(float4*)&Ws[kr][c4] = *(const float4*)&W[(kb + kr) * 128 + c4];
        }
        {
            int ar = t >> 2;              // 64 rows, 4 threads/row
            int cu = (t & 3) * 8;         // 8 uints per thread (32 uints/row-kblock)
            int row = row0 + ar; if (row >= GN) row = GN - 1;
            uint4 av0 = *(const uint4*)&A[(size_t)row * 64 + (kb >> 1) + cu];
            uint4 av1 = *(const uint4*)&A[(size_t)row * 64 + (kb >> 1) + cu + 4];
            unsigned int uu[8] = {av0.x, av0.y, av0.z, av0.w, av1.x, av1.y, av1.z, av1.w};
#pragma unroll
            for (int i = 0; i < 8; i++) {
                As[ar][(cu + i) * 2 + 0] = bflo(uu[i]);
                As[ar][(cu + i) * 2 + 1] = bfhi(uu[i]);
            }
        }
        __syncthreads();
#pragma unroll 4
        for (int k = 0; k < 64; k++) {
            float4 b0 = *(float4*)&Ws[k][tx * 4];
            float4 b1 = *(float4*)&Ws[k][64 + tx * 4];
#pragma unroll
            for (int r = 0; r < 4; r++) {
                float a = As[ty * 4 + r][k];
                accA[r].x = fmaf(a, b0.x, accA[r].x); accA[r].y = fmaf(a, b0.y, accA[r].y);
                accA[r].z = fmaf(a, b0.z, accA[r].z); accA[r].w = fmaf(a, b0.w, accA[r].w);
                accB[r].x = fmaf(a, b1.x, accB[r].x); accB[r].y = fmaf(a, b1.y, accB[r].y);
                accB[r].z = fmaf(a, b1.z, accB[r].z); accB[r].w = fmaf(a, b1.w, accB[r].w);
            }
        }
        __syncthreads();
    }
#pragma unroll
    for (int r = 0; r < 4; r++) {
        int row = row0 + ty * 4 + r;
        if (row >= GN) continue;
        float dv = dinv[row];
        float4 oA = accA[r], oB = accB[r];
        uint2 pA, pB;
        pA.x = f2bf(oA.x * dv) | (f2bf(oA.y * dv) << 16);
        pA.y = f2bf(oA.z * dv) | (f2bf(oA.w * dv) << 16);
        pB.x = f2bf(oB.x * dv) | (f2bf(oB.y * dv) << 16);
        pB.y = f2bf(oB.z * dv) | (f2bf(oB.w * dv) << 16);
        *(uint2*)&C[(size_t)row * 64 + tx * 2] = pA;
        *(uint2*)&C[(size_t)row * 64 + 32 + tx * 2] = pB;
    }
}

// ------------- aggregation: h[v] = relu(dinv[v]*(sum ts[src] + ts[v]) + b), bf16 out
// 16-lane groups: 4 nodes/wave, lane16 loads one uint4 (16B) of the 256B row.
// Per wave-instruction: 4 whole rows gathered (vs 1 before) -> 4x fewer VMEM/shfl per edge.
__global__ __launch_bounds__(256) void k_aggregate(const unsigned int* __restrict__ ts,
                                                   const int* __restrict__ offsets,
                                                   const int* __restrict__ csr_src,
                                                   const float* __restrict__ dinv,
                                                   const float* __restrict__ bias,
                                                   unsigned int* __restrict__ out) {
    int t = threadIdx.x;
    int wave = t >> 6, lane = t & 63;
    int grp = lane >> 4, l16 = lane & 15;
    int node = blockIdx.x * 16 + wave * 4 + grp;
    if (node >= GN) return;
    int beg = offsets[node];
    int end = offsets[node + 1];
    float di = dinv[node];
    const uint4* t4 = (const uint4*)ts;  // one row = 16 uint4
    float acc[8] = {0.f, 0.f, 0.f, 0.f, 0.f, 0.f, 0.f, 0.f};
    int srcbase = grp * 16;
    for (int base = beg; base < end; ) {
        int n = end - base; if (n > 16) n = 16;
        int myidx = (l16 < n) ? csr_src[base + l16] : 0;
        if (n == 16) {
            uint4 u[16];
#pragma unroll
            for (int j = 0; j < 16; j++) {
                int s = __shfl(myidx, srcbase + j);
                u[j] = t4[(size_t)s * 16 + l16];
            }
#pragma unroll
            for (int j = 0; j < 16; j++) {
                acc[0] += bflo(u[j].x); acc[1] += bfhi(u[j].x);
                acc[2] += bflo(u[j].y); acc[3] += bfhi(u[j].y);
                acc[4] += bflo(u[j].z); acc[5] += bfhi(u[j].z);
                acc[6] += bflo(u[j].w); acc[7] += bfhi(u[j].w);
            }
        } else {
            for (int j = 0; j < n; j++) {
                int s = __shfl(myidx, srcbase + j);
                uint4 u = t4[(size_t)s * 16 + l16];
                acc[0] += bflo(u.x); acc[1] += bfhi(u.x);
                acc[2] += bflo(u.y); acc[3] += bfhi(u.y);
                acc[4] += bflo(u.z); acc[5] += bfhi(u.z);
                acc[6] += bflo(u.w); acc[7] += bfhi(u.w);
            }
        }
        base += n;
    }
    uint4 su = t4[(size_t)node * 16 + l16];  // self-loop (pre-scaled by dinv[node])
    float sv[8] = {bflo(su.x), bfhi(su.x), bflo(su.y), bfhi(su.y),
                   bflo(su.z), bfhi(su.z), bflo(su.w), bfhi(su.w)};
    float4 b0 = *(const float4*)&bias[l16 * 8];
    float4 b1 = *(const float4*)&bias[l16 * 8 + 4];
    float bb[8] = {b0.x, b0.y, b0.z, b0.w, b1.x, b1.y, b1.z, b1.w};
    float o[8];
#pragma unroll
    for (int i = 0; i < 8; i++)
        o[i] = fmaxf(fmaf(di, acc[i] + sv[i], bb[i]), 0.f);
    uint4 po;
    po.x = f2bf(o[0]) | (f2bf(o[1]) << 16);
    po.y = f2bf(o[2]) | (f2bf(o[3]) << 16);
    po.z = f2bf(o[4]) | (f2bf(o[5]) << 16);
    po.w = f2bf(o[6]) | (f2bf(o[7]) << 16);
    ((uint4*)out)[(size_t)node * 16 + l16] = po;
}

// ------------- mean pool per graph (batch sorted), bf16 h input -------------
__global__ __launch_bounds__(256) void k_pool(const unsigned int* __restrict__ h,
                                              const int* __restrict__ batch,
                                              float* __restrict__ pooled) {
    int g = blockIdx.x;
    int t = threadIdx.x;
    int f = t & 63, part = t >> 6;  // f: uint col, part: 4-way row split
    int lo = 0, hi = GN;
    while (lo < hi) { int m = (lo + hi) >> 1; if (batch[m] < g) lo = m + 1; else hi = m; }
    int start = lo;
    hi = GN;
    while (lo < hi) { int m = (lo + hi) >> 1; if (batch[m] <= g) lo = m + 1; else hi = m; }
    int end = lo;
    float ax = 0.f, ay = 0.f;
    for (int i = start + part; i < end; i += 4) {
        unsigned int u = h[(size_t)i * 64 + f];
        ax += bflo(u); ay += bfhi(u);
    }
    __shared__ float redx[256], redy[256];
    redx[t] = ax; redy[t] = ay;
    __syncthreads();
    if (part == 0) {
        float sx = redx[f] + redx[f + 64] + redx[f + 128] + redx[f + 192];
        float sy = redy[f] + redy[f + 64] + redy[f + 128] + redy[f + 192];
        float inv = 1.0f / fmaxf((float)(end - start), 1.0f);
        pooled[g * 128 + 2 * f + 0] = sx * inv;
        pooled[g * 128 + 2 * f + 1] = sy * inv;
    }
}

// ------------- value head -------------
__global__ void k_value(const float* __restrict__ pooled, const float* __restrict__ Wv,
                        const float* __restrict__ bv, float* __restrict__ out) {
    int g = threadIdx.x;
    const float4* p4 = (const float4*)(pooled + g * 128);
    const float4* w4 = (const float4*)Wv;
    float s = 0.f;
#pragma unroll 8
    for (int i = 0; i < 32; i++) {
        float4 a = p4[i], b = w4[i];
        s += a.x * b.x + a.y * b.y + a.z * b.z + a.w * b.w;
    }
    out[g] = tanhf(s + bv[0]);
}

// ------------- policy head -------------
__global__ __launch_bounds__(256) void k_policy(const float* __restrict__ pooled,
                                                const float* __restrict__ Wp,
                                                const float* __restrict__ bp,
                                                float* __restrict__ out) {
    int g = blockIdx.x;
    int t = threadIdx.x;
    __shared__ float pr[128];
    __shared__ float red[256];
    if (t < 128) pr[t] = pooled[g * 128 + t];
    __syncthreads();
    float acc0 = bp[t + 0], acc1 = bp[t + 256], acc2 = bp[t + 512], acc3 = bp[t + 768];
    for (int k = 0; k < 128; k++) {
        float pv = pr[k];
        const float* wr = Wp + (size_t)k * 1024;
        acc0 = fmaf(pv, wr[t + 0],   acc0);
        acc1 = fmaf(pv, wr[t + 256], acc1);
        acc2 = fmaf(pv, wr[t + 512], acc2);
        acc3 = fmaf(pv, wr[t + 768], acc3);
    }
    float m = fmaxf(fmaxf(acc0, acc1), fmaxf(acc2, acc3));
    red[t] = m;
    __syncthreads();
    for (int off = 128; off > 0; off >>= 1) {
        if (t < off) red[t] = fmaxf(red[t], red[t + off]);
        __syncthreads();
    }
    float mx = red[0];
    __syncthreads();
    float e0 = __expf(acc0 - mx), e1 = __expf(acc1 - mx);
    float e2 = __expf(acc2 - mx), e3 = __expf(acc3 - mx);
    red[t] = (e0 + e1) + (e2 + e3);
    __syncthreads();
    for (int off = 128; off > 0; off >>= 1) {
        if (t < off) red[t] += red[t + off];
        __syncthreads();
    }
    float inv = 1.0f / red[0];
    out[(size_t)g * 1024 + t + 0]   = e0 * inv;
    out[(size_t)g * 1024 + t + 256] = e1 * inv;
    out[(size_t)g * 1024 + t + 512] = e2 * inv;
    out[(size_t)g * 1024 + t + 768] = e3 * inv;
}

extern "C" void kernel_launch(void* const* d_in, const int* in_sizes, int n_in,
                              void* d_out, int out_size, void* d_ws, size_t ws_size,
                              hipStream_t stream) {
    const float* x    = (const float*)d_in[0];
    const int*   ei   = (const int*)d_in[1];
    const int*   srcA = ei;        // edge_index[0]
    const int*   dstA = ei + GE;   // edge_index[1]
    const int*   batch = (const int*)d_in[2];
    const float* W1 = (const float*)d_in[3];
    const float* b1 = (const float*)d_in[4];
    const float* W2 = (const float*)d_in[5];
    const float* b2 = (const float*)d_in[6];
    const float* Wv = (const float*)d_in[7];
    const float* bv = (const float*)d_in[8];
    const float* Wp = (const float*)d_in[9];
    const float* bp = (const float*)d_in[10];
    float* out = (float*)d_out;

    char* ws = (char*)d_ws;
    unsigned int* bufH = (unsigned int*)ws;  ws += (size_t)GN * 64 * 4;  // 25.6 MB bf16 h
    unsigned int* ts_bf = (unsigned int*)ws; ws += (size_t)GN * 64 * 4;  // 25.6 MB bf16 ts
    float* pooled = (float*)ws;      ws += (size_t)GB * 128 * 4;
    float* dinv = (float*)ws;        ws += (size_t)100352 * 4;
    int*   csr_src = (int*)ws;       ws += (size_t)GE * 4;               // 12.8 MB
    int*   offsets = (int*)ws;       ws += (size_t)100352 * 4;
    int*   coarse_cnt = (int*)ws;    ws += 512 * 4;
    int*   gcur = (int*)ws;          ws += 512 * 4;
    int*   cbase = (int*)ws;         ws += 512 * 4;
    unsigned int* binned = ts_bf;    // alias: consumed by k_sort2 before gemm1 writes ts

    // --- CSR build ---
    hipMemsetAsync(coarse_cnt, 0, NBUK * 4, stream);
    k_hist_coarse<<<1024, 256, 0, stream>>>(dstA, coarse_cnt);
    k_scan_coarse<<<1, 256, 0, stream>>>(coarse_cnt, gcur, cbase, offsets);
    k_bin1<<<NBIN1, 256, 0, stream>>>(srcA, dstA, gcur, binned);
    k_sort2<<<NBUK, 256, 0, stream>>>(binned, cbase, csr_src, offsets, dinv);

    // --- layer 1: ts = bf16(dinv .* (x @ W1)); h1 = relu(dinv*(gather + self) + b1) ---
    k_gemm_f32<<<(GN + 63) / 64, 256, 0, stream>>>(x, W1, dinv, ts_bf);
    k_aggregate<<<(GN + 15) / 16, 256, 0, stream>>>(ts_bf, offsets, csr_src, dinv, b1, bufH);

    // --- layer 2 ---
    k_gemm_bf16<<<(GN + 63) / 64, 256, 0, stream>>>(bufH, W2, dinv, ts_bf);
    k_aggregate<<<(GN + 15) / 16, 256, 0, stream>>>(ts_bf, offsets, csr_src, dinv, b2, bufH);

    // --- pool + heads ---
    k_pool<<<GB, 256, 0, stream>>>(bufH, batch, pooled);
    k_value<<<1, 256, 0, stream>>>(pooled, Wv, bv, out);
    k_policy<<<GB, 256, 0, stream>>>(pooled, Wp, bp, out + GB);
}

// Round 10
// 427.613 us; speedup vs baseline: 1.1145x; 1.1092x over previous
//
#include <hip/hip_runtime.h>
#include <hip/hip_bf16.h>

#define GN 100000   // nodes
#define GE 3200000  // edges
#define GH 128      // feature/hidden width
#define GA 1024     // actions
#define GB 256      // graphs

#define NBUK 391    // buckets of 256 nodes (ceil(GN/256))
#define B1BLK 5120  // edges per k_bin1 block
#define NBIN1 625   // k_bin1 blocks: 625 * 5120 = GE exactly

typedef __attribute__((ext_vector_type(8))) short short8v;
typedef __attribute__((ext_vector_type(4))) float f32x4v;

// round-to-nearest-even fp32 -> bf16 (as ushort)
__device__ __forceinline__ unsigned int f2bf(float f) {
    unsigned int u = __float_as_uint(f);
    return (u + 0x7fffu + ((u >> 16) & 1u)) >> 16;
}
__device__ __forceinline__ float bflo(unsigned int u) { return __uint_as_float(u << 16); }
__device__ __forceinline__ float bfhi(unsigned int u) { return __uint_as_float(u & 0xffff0000u); }

// ---------------- CSR build: coarse bin (LDS-staged coalesced) + in-bucket sort ----

__global__ __launch_bounds__(256) void k_hist_coarse(const int* __restrict__ dst,
                                                     int* __restrict__ cnt) {
    __shared__ int h[NBUK];
    int t = threadIdx.x;
    for (int i = t; i < NBUK; i += 256) h[i] = 0;
    __syncthreads();
    int beg = blockIdx.x * 3125;  // 1024 blocks * 3125 = GE exactly
    for (int e = beg + t; e < beg + 3125; e += 256)
        atomicAdd(&h[dst[e] >> 8], 1);
    __syncthreads();
    for (int i = t; i < NBUK; i += 256) {
        int c = h[i];
        if (c) atomicAdd(&cnt[i], c);
    }
}

// parallel exclusive scan of 391 counts (padded to 512), 2 elements/thread
__global__ __launch_bounds__(256) void k_scan_coarse(const int* __restrict__ cnt,
                                                     int* __restrict__ gcur,
                                                     int* __restrict__ cbase,
                                                     int* __restrict__ offsets) {
    __shared__ int wsc[4];
    int t = threadIdx.x;
    int i0 = 2 * t, i1 = 2 * t + 1;
    int v0 = (i0 < NBUK) ? cnt[i0] : 0;
    int v1 = (i1 < NBUK) ? cnt[i1] : 0;
    int s = v0 + v1;
    int lane = t & 63, w = t >> 6;
    int x = s;
#pragma unroll
    for (int off = 1; off < 64; off <<= 1) {
        int y = __shfl_up(x, off);
        if (lane >= off) x += y;
    }
    if (lane == 63) wsc[w] = x;
    __syncthreads();
    int wo = 0;
#pragma unroll
    for (int i = 0; i < 4; i++)
        if (i < w) wo += wsc[i];
    int excl = wo + x - s;
    if (i0 < NBUK) { cbase[i0] = excl; gcur[i0] = excl; }
    if (i1 < NBUK) { cbase[i1] = excl + v0; gcur[i1] = excl + v0; }
    if (t == 0) { cbase[NBUK] = GE; offsets[GN] = GE; }
}

// block-local LDS counting sort into 391 buckets, then coalesced run writes
__global__ __launch_bounds__(256) void k_bin1(const int* __restrict__ src,
                                              const int* __restrict__ dst,
                                              int* __restrict__ gcur,
                                              unsigned int* __restrict__ binned) {
    __shared__ int hist[512], lstart[512];
    __shared__ int curl[NBUK], gbase[NBUK];
    __shared__ unsigned int srec[B1BLK];
    __shared__ unsigned short sbuk[B1BLK];
    __shared__ int wsc[4];
    int t = threadIdx.x;
    hist[t] = 0; hist[t + 256] = 0;
    __syncthreads();
    int beg = blockIdx.x * B1BLK;
    unsigned int rec[20]; int bukv[20];
#pragma unroll
    for (int k = 0; k < 20; k++) {          // 256 * 20 = 5120 = B1BLK exactly
        int e = beg + t + k * 256;
        int d = dst[e];
        rec[k] = (unsigned int)src[e] | ((unsigned int)(d & 255) << 17);
        bukv[k] = d >> 8;
        atomicAdd(&hist[bukv[k]], 1);
    }
    __syncthreads();
    // parallel scan of 512 bucket counts, 2/thread
    int v0 = hist[2 * t], v1 = hist[2 * t + 1];
    int s = v0 + v1;
    int lane = t & 63, w = t >> 6;
    int x = s;
#pragma unroll
    for (int off = 1; off < 64; off <<= 1) {
        int y = __shfl_up(x, off);
        if (lane >= off) x += y;
    }
    if (lane == 63) wsc[w] = x;
    __syncthreads();
    int wo = 0;
#pragma unroll
    for (int i = 0; i < 4; i++)
        if (i < w) wo += wsc[i];
    int excl = wo + x - s;
    lstart[2 * t] = excl;
    lstart[2 * t + 1] = excl + v0;
    __syncthreads();
    for (int i = t; i < NBUK; i += 256) {
        curl[i] = lstart[i];
        int c = hist[i];
        gbase[i] = c ? atomicAdd(&gcur[i], c) : 0;
    }
    __syncthreads();
#pragma unroll
    for (int k = 0; k < 20; k++) {
        int p = atomicAdd(&curl[bukv[k]], 1);
        srec[p] = rec[k];
        sbuk[p] = (unsigned short)bukv[k];
    }
    __syncthreads();
    // coalesced run writes: consecutive threads -> consecutive slots -> consecutive addrs
    for (int i = t; i < B1BLK; i += 256) {
        int b = sbuk[i];
        binned[gbase[b] + (i - lstart[b])] = srec[i];
    }
}

// one 256-thread block per bucket: sort to node granularity -> CSR + dinv
__global__ __launch_bounds__(256) void k_sort2(const unsigned int* __restrict__ binned,
                                               const int* __restrict__ cbase,
                                               int* __restrict__ csr_src,
                                               int* __restrict__ offsets,
                                               float* __restrict__ dinv) {
    int b = blockIdx.x, t = threadIdx.x;
    __shared__ int hist[256], cur[256], wsum[4];
    hist[t] = 0;
    __syncthreads();
    int rbase = cbase[b], rend = cbase[b + 1];
    for (int e = rbase + t; e < rend; e += 256)
        atomicAdd(&hist[(binned[e] >> 17) & 255], 1);
    __syncthreads();
    int h = hist[t];
    int lane = t & 63, w = t >> 6;
    int x = h;
#pragma unroll
    for (int off = 1; off < 64; off <<= 1) {
        int y = __shfl_up(x, off);
        if (lane >= off) x += y;
    }
    if (lane == 63) wsum[w] = x;
    __syncthreads();
    int wo = 0;
#pragma unroll
    for (int i = 0; i < 4; i++)
        if (i < w) wo += wsum[i];
    int excl = wo + x - h;  // exclusive prefix within bucket
    int node = (b << 8) + t;
    if (node < GN) {
        offsets[node] = rbase + excl;
        dinv[node] = rsqrtf((float)(h + 1));  // +1 self-loop
    }
    cur[t] = excl;
    __syncthreads();
    for (int e = rbase + t; e < rend; e += 256) {
        unsigned int v = binned[e];
        int dl = (v >> 17) & 255;
        int p = atomicAdd(&cur[dl], 1);
        csr_src[rbase + p] = (int)(v & 0x1FFFF);
    }
}

// ---------------- fp32 -> bf16-packed conversion (for x) ----------------
__global__ __launch_bounds__(256) void k_cvt(const float* __restrict__ x,
                                             unsigned int* __restrict__ xb) {
    size_t i = (size_t)blockIdx.x * 256 + threadIdx.x;  // over GN*64 uints
    if (i < (size_t)GN * 64) {
        float2 v = ((const float2*)x)[i];
        xb[i] = f2bf(v.x) | (f2bf(v.y) << 16);
    }
}

// ---------------- MFMA GEMM: C = bf16(dinv .* (A_bf16 @ bf16(W))) ----------------
// 64 rows/block, 4 waves; wave w computes rows w*16..w*16+15 x all 128 cols
// via 8 tiles of mfma_f32_16x16x32_bf16 over 4 k-steps.
// A/B frag layout: lane = idx16 + 16*g holds elems k = g*8 + j (j=0..7).
// C/D layout (verified): col = lane&15, row = (lane>>4)*4 + reg.
__global__ __launch_bounds__(256) void k_gemm_mfma(const unsigned int* __restrict__ A,
                                                   const float* __restrict__ W,
                                                   const float* __restrict__ dinv,
                                                   unsigned int* __restrict__ C) {
    __shared__ unsigned short Wf[16384];  // frag-swizzled bf16 W (32 KB)
    __shared__ float Ct[64][128];         // epilogue staging (32 KB)
    int t = threadIdx.x;
    int row0 = blockIdx.x * 64;
    // stage W: coalesced global read, swizzled LDS write
    for (int i = 0; i < 64; i++) {
        int idx = t + 256 * i;            // linear over 128x128
        int k = idx >> 7, n = idx & 127;
        int qd = (((k >> 5) * 8 + (n >> 4)) * 64 + ((k >> 3) & 3) * 16 + (n & 15)) * 8 + (k & 7);
        Wf[qd] = (unsigned short)f2bf(W[idx]);
    }
    __syncthreads();
    int wv = t >> 6, lane = t & 63;
    int m16 = lane & 15, g = lane >> 4;
    f32x4v acc[8];
#pragma unroll
    for (int nb = 0; nb < 8; nb++) acc[nb] = (f32x4v){0.f, 0.f, 0.f, 0.f};
    int arow = row0 + wv * 16 + m16; if (arow >= GN) arow = GN - 1;
#pragma unroll
    for (int kb = 0; kb < 4; kb++) {
        uint4 av = *(const uint4*)&A[(size_t)arow * 64 + kb * 16 + g * 4];  // 8 bf16, k asc
        short8v af = *(short8v*)&av;
#pragma unroll
        for (int nb = 0; nb < 8; nb++) {
            short8v bf = *(short8v*)&Wf[((kb * 8 + nb) * 64 + lane) * 8];
            acc[nb] = __builtin_amdgcn_mfma_f32_16x16x32_bf16(af, bf, acc[nb], 0, 0, 0);
        }
    }
#pragma unroll
    for (int nb = 0; nb < 8; nb++)
#pragma unroll
        for (int r = 0; r < 4; r++)
            Ct[wv * 16 + g * 4 + r][nb * 16 + m16] = acc[nb][r];
    __syncthreads();
    // pack + store: thread t -> row t>>2, 32-col chunk (t&3)
    int lr = t >> 2, ch = t & 3;
    int grow = row0 + lr;
    if (grow < GN) {
        float dv = dinv[grow];
#pragma unroll
        for (int q = 0; q < 4; q++) {
            int c0 = ch * 32 + q * 8;
            uint4 po;
            po.x = f2bf(Ct[lr][c0 + 0] * dv) | (f2bf(Ct[lr][c0 + 1] * dv) << 16);
            po.y = f2bf(Ct[lr][c0 + 2] * dv) | (f2bf(Ct[lr][c0 + 3] * dv) << 16);
            po.z = f2bf(Ct[lr][c0 + 4] * dv) | (f2bf(Ct[lr][c0 + 5] * dv) << 16);
            po.w = f2bf(Ct[lr][c0 + 6] * dv) | (f2bf(Ct[lr][c0 + 7] * dv) << 16);
            *(uint4*)&C[(size_t)grow * 64 + ch * 16 + q * 4] = po;
        }
    }
}

// ------------- aggregation: h[v] = relu(dinv[v]*(sum ts[src] + ts[v]) + b), bf16 out
// (round-7 form: 1 node/wave, lane = feature pair, coalesced index loads + shfl)
__global__ __launch_bounds__(256) void k_aggregate(const unsigned int* __restrict__ ts,
                                                   const int* __restrict__ offsets,
                                                   const int* __restrict__ csr_src,
                                                   const float* __restrict__ dinv,
                                                   const float* __restrict__ bias,
                                                   unsigned int* __restrict__ out) {
    int node = blockIdx.x * 4 + (threadIdx.x >> 6);
    if (node >= GN) return;
    int lane = threadIdx.x & 63;
    int beg = offsets[node];
    int end = offsets[node + 1];
    float di = dinv[node];
    float ax = 0.f, ay = 0.f;
    for (int base = beg; base < end; base += 64) {
        int n = end - base; if (n > 64) n = 64;
        int myidx = (lane < n) ? csr_src[base + lane] : 0;  // coalesced index load
        int k = 0;
        for (; k + 16 <= n; k += 16) {
            unsigned int u[16];
#pragma unroll
            for (int q = 0; q < 16; q++) {
                int s = __shfl(myidx, k + q);
                u[q] = ts[s * 64 + lane];
            }
#pragma unroll
            for (int q = 0; q < 16; q++) { ax += bflo(u[q]); ay += bfhi(u[q]); }
        }
        for (; k + 4 <= n; k += 4) {
            unsigned int u[4];
#pragma unroll
            for (int q = 0; q < 4; q++) {
                int s = __shfl(myidx, k + q);
                u[q] = ts[s * 64 + lane];
            }
#pragma unroll
            for (int q = 0; q < 4; q++) { ax += bflo(u[q]); ay += bfhi(u[q]); }
        }
        for (; k < n; k++) {
            int s = __shfl(myidx, k);
            unsigned int u = ts[s * 64 + lane];
            ax += bflo(u); ay += bfhi(u);
        }
    }
    unsigned int su = ts[(size_t)node * 64 + lane];  // self-loop (pre-scaled)
    float bx = bias[lane * 2 + 0], by = bias[lane * 2 + 1];
    float ox = fmaxf(fmaf(di, ax + bflo(su), bx), 0.f);
    float oy = fmaxf(fmaf(di, ay + bfhi(su), by), 0.f);
    out[(size_t)node * 64 + lane] = f2bf(ox) | (f2bf(oy) << 16);
}

// ------------- mean pool per graph (batch sorted), bf16 h input -------------
__global__ __launch_bounds__(256) void k_pool(const unsigned int* __restrict__ h,
                                              const int* __restrict__ batch,
                                              float* __restrict__ pooled) {
    int g = blockIdx.x;
    int t = threadIdx.x;
    int f = t & 63, part = t >> 6;  // f: uint col, part: 4-way row split
    int lo = 0, hi = GN;
    while (lo < hi) { int m = (lo + hi) >> 1; if (batch[m] < g) lo = m + 1; else hi = m; }
    int start = lo;
    hi = GN;
    while (lo < hi) { int m = (lo + hi) >> 1; if (batch[m] <= g) lo = m + 1; else hi = m; }
    int end = lo;
    float ax = 0.f, ay = 0.f;
    for (int i = start + part; i < end; i += 4) {
        unsigned int u = h[(size_t)i * 64 + f];
        ax += bflo(u); ay += bfhi(u);
    }
    __shared__ float redx[256], redy[256];
    redx[t] = ax; redy[t] = ay;
    __syncthreads();
    if (part == 0) {
        float sx = redx[f] + redx[f + 64] + redx[f + 128] + redx[f + 192];
        float sy = redy[f] + redy[f + 64] + redy[f + 128] + redy[f + 192];
        float inv = 1.0f / fmaxf((float)(end - start), 1.0f);
        pooled[g * 128 + 2 * f + 0] = sx * inv;
        pooled[g * 128 + 2 * f + 1] = sy * inv;
    }
}

// ------------- value head -------------
__global__ void k_value(const float* __restrict__ pooled, const float* __restrict__ Wv,
                        const float* __restrict__ bv, float* __restrict__ out) {
    int g = threadIdx.x;
    const float4* p4 = (const float4*)(pooled + g * 128);
    const float4* w4 = (const float4*)Wv;
    float s = 0.f;
#pragma unroll 8
    for (int i = 0; i < 32; i++) {
        float4 a = p4[i], b = w4[i];
        s += a.x * b.x + a.y * b.y + a.z * b.z + a.w * b.w;
    }
    out[g] = tanhf(s + bv[0]);
}

// ------------- policy head -------------
__global__ __launch_bounds__(256) void k_policy(const float* __restrict__ pooled,
                                                const float* __restrict__ Wp,
                                                const float* __restrict__ bp,
                                                float* __restrict__ out) {
    int g = blockIdx.x;
    int t = threadIdx.x;
    __shared__ float pr[128];
    __shared__ float red[256];
    if (t < 128) pr[t] = pooled[g * 128 + t];
    __syncthreads();
    float acc0 = bp[t + 0], acc1 = bp[t + 256], acc2 = bp[t + 512], acc3 = bp[t + 768];
    for (int k = 0; k < 128; k++) {
        float pv = pr[k];
        const float* wr = Wp + (size_t)k * 1024;
        acc0 = fmaf(pv, wr[t + 0],   acc0);
        acc1 = fmaf(pv, wr[t + 256], acc1);
        acc2 = fmaf(pv, wr[t + 512], acc2);
        acc3 = fmaf(pv, wr[t + 768], acc3);
    }
    float m = fmaxf(fmaxf(acc0, acc1), fmaxf(acc2, acc3));
    red[t] = m;
    __syncthreads();
    for (int off = 128; off > 0; off >>= 1) {
        if (t < off) red[t] = fmaxf(red[t], red[t + off]);
        __syncthreads();
    }
    float mx = red[0];
    __syncthreads();
    float e0 = __expf(acc0 - mx), e1 = __expf(acc1 - mx);
    float e2 = __expf(acc2 - mx), e3 = __expf(acc3 - mx);
    red[t] = (e0 + e1) + (e2 + e3);
    __syncthreads();
    for (int off = 128; off > 0; off >>= 1) {
        if (t < off) red[t] += red[t + off];
        __syncthreads();
    }
    float inv = 1.0f / red[0];
    out[(size_t)g * 1024 + t + 0]   = e0 * inv;
    out[(size_t)g * 1024 + t + 256] = e1 * inv;
    out[(size_t)g * 1024 + t + 512] = e2 * inv;
    out[(size_t)g * 1024 + t + 768] = e3 * inv;
}

extern "C" void kernel_launch(void* const* d_in, const int* in_sizes, int n_in,
                              void* d_out, int out_size, void* d_ws, size_t ws_size,
                              hipStream_t stream) {
    const float* x    = (const float*)d_in[0];
    const int*   ei   = (const int*)d_in[1];
    const int*   srcA = ei;        // edge_index[0]
    const int*   dstA = ei + GE;   // edge_index[1]
    const int*   batch = (const int*)d_in[2];
    const float* W1 = (const float*)d_in[3];
    const float* b1 = (const float*)d_in[4];
    const float* W2 = (const float*)d_in[5];
    const float* b2 = (const float*)d_in[6];
    const float* Wv = (const float*)d_in[7];
    const float* bv = (const float*)d_in[8];
    const float* Wp = (const float*)d_in[9];
    const float* bp = (const float*)d_in[10];
    float* out = (float*)d_out;

    char* ws = (char*)d_ws;
    unsigned int* bufH = (unsigned int*)ws;  ws += (size_t)GN * 64 * 4;  // 25.6 MB bf16 h
    unsigned int* ts_bf = (unsigned int*)ws; ws += (size_t)GN * 64 * 4;  // 25.6 MB bf16 ts
    unsigned int* xbf = (unsigned int*)ws;   ws += (size_t)GN * 64 * 4;  // 25.6 MB bf16 x
    float* pooled = (float*)ws;      ws += (size_t)GB * 128 * 4;
    float* dinv = (float*)ws;        ws += (size_t)100352 * 4;
    int*   csr_src = (int*)ws;       ws += (size_t)GE * 4;               // 12.8 MB
    int*   offsets = (int*)ws;       ws += (size_t)100352 * 4;
    int*   coarse_cnt = (int*)ws;    ws += 512 * 4;
    int*   gcur = (int*)ws;          ws += 512 * 4;
    int*   cbase = (int*)ws;         ws += 512 * 4;
    unsigned int* binned = ts_bf;    // alias: consumed by k_sort2 before gemm1 writes ts

    // --- CSR build + x conversion (independent) ---
    hipMemsetAsync(coarse_cnt, 0, NBUK * 4, stream);
    k_cvt<<<(GN * 64 + 255) / 256, 256, 0, stream>>>(x, xbf);
    k_hist_coarse<<<1024, 256, 0, stream>>>(dstA, coarse_cnt);
    k_scan_coarse<<<1, 256, 0, stream>>>(coarse_cnt, gcur, cbase, offsets);
    k_bin1<<<NBIN1, 256, 0, stream>>>(srcA, dstA, gcur, binned);
    k_sort2<<<NBUK, 256, 0, stream>>>(binned, cbase, csr_src, offsets, dinv);

    // --- layer 1: ts = bf16(dinv .* (x @ W1)); h1 = relu(dinv*(gather + self) + b1) ---
    k_gemm_mfma<<<(GN + 63) / 64, 256, 0, stream>>>(xbf, W1, dinv, ts_bf);
    k_aggregate<<<GN / 4, 256, 0, stream>>>(ts_bf, offsets, csr_src, dinv, b1, bufH);

    // --- layer 2 ---
    k_gemm_mfma<<<(GN + 63) / 64, 256, 0, stream>>>(bufH, W2, dinv, ts_bf);
    k_aggregate<<<GN / 4, 256, 0, stream>>>(ts_bf, offsets, csr_src, dinv, b2, bufH);

    // --- pool + heads ---
    k_pool<<<GB, 256, 0, stream>>>(bufH, batch, pooled);
    k_value<<<1, 256, 0, stream>>>(pooled, Wv, bv, out);
    k_policy<<<GB, 256, 0, stream>>>(pooled, Wp, bp, out + GB);
}

// Round 11
// 372.805 us; speedup vs baseline: 1.2783x; 1.1470x over previous
//
#include <hip/hip_runtime.h>
#include <hip/hip_bf16.h>

#define GN 100000   // nodes
#define GE 3200000  // edges
#define GH 128      // feature/hidden width
#define GA 1024     // actions
#define GB 256      // graphs

#define NBUK 391    // buckets of 256 nodes (ceil(GN/256))
#define BCAP 12288  // fixed bucket capacity (mean 8192, sigma~90 -> +45 sigma)
#define B1BLK 5120  // edges per k_bin1 block
#define NBIN1 625   // k_bin1 blocks: 625 * 5120 = GE exactly

typedef __attribute__((ext_vector_type(8))) short short8v;
typedef __attribute__((ext_vector_type(4))) float f32x4v;

// round-to-nearest-even fp32 -> bf16 (as ushort)
__device__ __forceinline__ unsigned int f2bf(float f) {
    unsigned int u = __float_as_uint(f);
    return (u + 0x7fffu + ((u >> 16) & 1u)) >> 16;
}
__device__ __forceinline__ float bflo(unsigned int u) { return __uint_as_float(u << 16); }
__device__ __forceinline__ float bfhi(unsigned int u) { return __uint_as_float(u & 0xffff0000u); }

// W frag-swizzle address: element (k,n) of 128x128 -> ushort index
__device__ __forceinline__ int wswz(int k, int n) {
    return (((k >> 5) * 8 + (n >> 4)) * 64 + ((k >> 3) & 3) * 16 + (n & 15)) * 8 + (k & 7);
}

// ---------------- prep: W1/W2 -> bf16 frag-swizzled; init bucket cursors ----------
__global__ __launch_bounds__(256) void k_prep(const float* __restrict__ W1,
                                              const float* __restrict__ W2,
                                              unsigned short* __restrict__ Wsw1,
                                              unsigned short* __restrict__ Wsw2,
                                              int* __restrict__ gcur) {
    int b = blockIdx.x, t = threadIdx.x;
    if (b < 64) {
        int idx = b * 256 + t;
        int k = idx >> 7, n = idx & 127;
        Wsw1[wswz(k, n)] = (unsigned short)f2bf(W1[idx]);
    } else if (b < 128) {
        int idx = (b - 64) * 256 + t;
        int k = idx >> 7, n = idx & 127;
        Wsw2[wswz(k, n)] = (unsigned short)f2bf(W2[idx]);
    } else {
        for (int i = t; i < NBUK; i += 256) gcur[i] = i * BCAP;
    }
}

// ---------------- bin1: block-local LDS counting sort into 391 buckets ------------
__global__ __launch_bounds__(256) void k_bin1(const int* __restrict__ src,
                                              const int* __restrict__ dst,
                                              int* __restrict__ gcur,
                                              unsigned int* __restrict__ binned) {
    __shared__ int hist[512], lstart[512];
    __shared__ int curl[NBUK], gbase[NBUK];
    __shared__ unsigned int srec[B1BLK];
    __shared__ unsigned short sbuk[B1BLK];
    __shared__ int wsc[4];
    int t = threadIdx.x;
    hist[t] = 0; hist[t + 256] = 0;
    __syncthreads();
    int beg = blockIdx.x * B1BLK;
    unsigned int rec[20]; int bukv[20];
#pragma unroll
    for (int k = 0; k < 20; k++) {          // 256 * 20 = 5120 = B1BLK exactly
        int e = beg + t + k * 256;
        int d = dst[e];
        rec[k] = (unsigned int)src[e] | ((unsigned int)(d & 255) << 17);
        bukv[k] = d >> 8;
        atomicAdd(&hist[bukv[k]], 1);
    }
    __syncthreads();
    // parallel scan of 512 bucket counts, 2/thread
    int v0 = hist[2 * t], v1 = hist[2 * t + 1];
    int s = v0 + v1;
    int lane = t & 63, w = t >> 6;
    int x = s;
#pragma unroll
    for (int off = 1; off < 64; off <<= 1) {
        int y = __shfl_up(x, off);
        if (lane >= off) x += y;
    }
    if (lane == 63) wsc[w] = x;
    __syncthreads();
    int wo = 0;
#pragma unroll
    for (int i = 0; i < 4; i++)
        if (i < w) wo += wsc[i];
    int excl = wo + x - s;
    lstart[2 * t] = excl;
    lstart[2 * t + 1] = excl + v0;
    __syncthreads();
    for (int i = t; i < NBUK; i += 256) {
        curl[i] = lstart[i];
        int c = hist[i];
        gbase[i] = c ? atomicAdd(&gcur[i], c) : 0;
    }
    __syncthreads();
#pragma unroll
    for (int k = 0; k < 20; k++) {
        int p = atomicAdd(&curl[bukv[k]], 1);
        srec[p] = rec[k];
        sbuk[p] = (unsigned short)bukv[k];
    }
    __syncthreads();
    // coalesced run writes: consecutive threads -> consecutive slots -> consecutive addrs
    for (int i = t; i < B1BLK; i += 256) {
        int b = sbuk[i];
        binned[gbase[b] + (i - lstart[b])] = srec[i];
    }
}

// ---------------- sort2: one block per bucket -> per-node CSR (padded) + dinv -----
__global__ __launch_bounds__(256) void k_sort2(const unsigned int* __restrict__ binned,
                                               const int* __restrict__ gcur,
                                               int* __restrict__ csr_src,
                                               int* __restrict__ nbeg,
                                               int* __restrict__ nend,
                                               float* __restrict__ dinv) {
    int b = blockIdx.x, t = threadIdx.x;
    __shared__ int hist[256], cur[256], wsum[4];
    hist[t] = 0;
    __syncthreads();
    int rbase = b * BCAP;
    int rend = gcur[b];  // rbase + count(b)
    for (int e = rbase + t; e < rend; e += 256)
        atomicAdd(&hist[(binned[e] >> 17) & 255], 1);
    __syncthreads();
    int h = hist[t];
    int lane = t & 63, w = t >> 6;
    int x = h;
#pragma unroll
    for (int off = 1; off < 64; off <<= 1) {
        int y = __shfl_up(x, off);
        if (lane >= off) x += y;
    }
    if (lane == 63) wsum[w] = x;
    __syncthreads();
    int wo = 0;
#pragma unroll
    for (int i = 0; i < 4; i++)
        if (i < w) wo += wsum[i];
    int excl = wo + x - h;  // exclusive prefix within bucket
    int node = (b << 8) + t;
    if (node < GN) {
        nbeg[node] = rbase + excl;
        nend[node] = rbase + excl + h;
        dinv[node] = rsqrtf((float)(h + 1));  // +1 self-loop
    }
    cur[t] = excl;
    __syncthreads();
    for (int e = rbase + t; e < rend; e += 256) {
        unsigned int v = binned[e];
        int dl = (v >> 17) & 255;
        int p = atomicAdd(&cur[dl], 1);
        csr_src[rbase + p] = (int)(v & 0x1FFFF);
    }
}

// ---------------- MFMA GEMM, layer 1: fp32 A, pre-swizzled bf16 W (global) -------
// 64 rows/block, 4 waves; wave w: rows w*16..+15 x 128 cols, 8 tiles x 4 k-steps.
// B frag loaded directly from global Wsw (32KB, L1-resident).
__global__ __launch_bounds__(256) void k_gemm1(const float* __restrict__ A,
                                               const unsigned short* __restrict__ Wsw,
                                               const float* __restrict__ dinv,
                                               unsigned int* __restrict__ C) {
    __shared__ float Ct[64][128];
    int t = threadIdx.x;
    int row0 = blockIdx.x * 64;
    int wv = t >> 6, lane = t & 63;
    int m16 = lane & 15, g = lane >> 4;
    f32x4v acc[8];
#pragma unroll
    for (int nb = 0; nb < 8; nb++) acc[nb] = (f32x4v){0.f, 0.f, 0.f, 0.f};
    int arow = row0 + wv * 16 + m16; if (arow >= GN) arow = GN - 1;
#pragma unroll
    for (int kb = 0; kb < 4; kb++) {
        const float* ap = &A[(size_t)arow * 128 + kb * 32 + g * 8];
        float4 a0 = *(const float4*)ap;
        float4 a1 = *(const float4*)(ap + 4);
        uint4 up;
        up.x = f2bf(a0.x) | (f2bf(a0.y) << 16);
        up.y = f2bf(a0.z) | (f2bf(a0.w) << 16);
        up.z = f2bf(a1.x) | (f2bf(a1.y) << 16);
        up.w = f2bf(a1.z) | (f2bf(a1.w) << 16);
        short8v af = *(short8v*)&up;
#pragma unroll
        for (int nb = 0; nb < 8; nb++) {
            short8v bf = *(const short8v*)&Wsw[((kb * 8 + nb) * 64 + lane) * 8];
            acc[nb] = __builtin_amdgcn_mfma_f32_16x16x32_bf16(af, bf, acc[nb], 0, 0, 0);
        }
    }
#pragma unroll
    for (int nb = 0; nb < 8; nb++)
#pragma unroll
        for (int r = 0; r < 4; r++)
            Ct[wv * 16 + g * 4 + r][nb * 16 + m16] = acc[nb][r];
    __syncthreads();
    int lr = t >> 2, ch = t & 3;
    int grow = row0 + lr;
    if (grow < GN) {
        float dv = dinv[grow];
#pragma unroll
        for (int q = 0; q < 4; q++) {
            int c0 = ch * 32 + q * 8;
            uint4 po;
            po.x = f2bf(Ct[lr][c0 + 0] * dv) | (f2bf(Ct[lr][c0 + 1] * dv) << 16);
            po.y = f2bf(Ct[lr][c0 + 2] * dv) | (f2bf(Ct[lr][c0 + 3] * dv) << 16);
            po.z = f2bf(Ct[lr][c0 + 4] * dv) | (f2bf(Ct[lr][c0 + 5] * dv) << 16);
            po.w = f2bf(Ct[lr][c0 + 6] * dv) | (f2bf(Ct[lr][c0 + 7] * dv) << 16);
            *(uint4*)&C[(size_t)grow * 64 + ch * 16 + q * 4] = po;
        }
    }
}

// ---------------- MFMA GEMM, layer 2: bf16-packed A ----------------
__global__ __launch_bounds__(256) void k_gemm2(const unsigned int* __restrict__ A,
                                               const unsigned short* __restrict__ Wsw,
                                               const float* __restrict__ dinv,
                                               unsigned int* __restrict__ C) {
    __shared__ float Ct[64][128];
    int t = threadIdx.x;
    int row0 = blockIdx.x * 64;
    int wv = t >> 6, lane = t & 63;
    int m16 = lane & 15, g = lane >> 4;
    f32x4v acc[8];
#pragma unroll
    for (int nb = 0; nb < 8; nb++) acc[nb] = (f32x4v){0.f, 0.f, 0.f, 0.f};
    int arow = row0 + wv * 16 + m16; if (arow >= GN) arow = GN - 1;
#pragma unroll
    for (int kb = 0; kb < 4; kb++) {
        uint4 av = *(const uint4*)&A[(size_t)arow * 64 + kb * 16 + g * 4];
        short8v af = *(short8v*)&av;
#pragma unroll
        for (int nb = 0; nb < 8; nb++) {
            short8v bf = *(const short8v*)&Wsw[((kb * 8 + nb) * 64 + lane) * 8];
            acc[nb] = __builtin_amdgcn_mfma_f32_16x16x32_bf16(af, bf, acc[nb], 0, 0, 0);
        }
    }
#pragma unroll
    for (int nb = 0; nb < 8; nb++)
#pragma unroll
        for (int r = 0; r < 4; r++)
            Ct[wv * 16 + g * 4 + r][nb * 16 + m16] = acc[nb][r];
    __syncthreads();
    int lr = t >> 2, ch = t & 3;
    int grow = row0 + lr;
    if (grow < GN) {
        float dv = dinv[grow];
#pragma unroll
        for (int q = 0; q < 4; q++) {
            int c0 = ch * 32 + q * 8;
            uint4 po;
            po.x = f2bf(Ct[lr][c0 + 0] * dv) | (f2bf(Ct[lr][c0 + 1] * dv) << 16);
            po.y = f2bf(Ct[lr][c0 + 2] * dv) | (f2bf(Ct[lr][c0 + 3] * dv) << 16);
            po.z = f2bf(Ct[lr][c0 + 4] * dv) | (f2bf(Ct[lr][c0 + 5] * dv) << 16);
            po.w = f2bf(Ct[lr][c0 + 6] * dv) | (f2bf(Ct[lr][c0 + 7] * dv) << 16);
            *(uint4*)&C[(size_t)grow * 64 + ch * 16 + q * 4] = po;
        }
    }
}

// ------------- aggregation: h[v] = relu(dinv[v]*(sum ts[src] + ts[v]) + b), bf16 out
__global__ __launch_bounds__(256) void k_aggregate(const unsigned int* __restrict__ ts,
                                                   const int* __restrict__ nbeg,
                                                   const int* __restrict__ nend,
                                                   const int* __restrict__ csr_src,
                                                   const float* __restrict__ dinv,
                                                   const float* __restrict__ bias,
                                                   unsigned int* __restrict__ out) {
    int node = blockIdx.x * 4 + (threadIdx.x >> 6);
    if (node >= GN) return;
    int lane = threadIdx.x & 63;
    int beg = nbeg[node];
    int end = nend[node];
    float di = dinv[node];
    float ax = 0.f, ay = 0.f;
    for (int base = beg; base < end; base += 64) {
        int n = end - base; if (n > 64) n = 64;
        int myidx = (lane < n) ? csr_src[base + lane] : 0;  // coalesced index load
        int k = 0;
        for (; k + 16 <= n; k += 16) {
            unsigned int u[16];
#pragma unroll
            for (int q = 0; q < 16; q++) {
                int s = __shfl(myidx, k + q);
                u[q] = ts[s * 64 + lane];
            }
#pragma unroll
            for (int q = 0; q < 16; q++) { ax += bflo(u[q]); ay += bfhi(u[q]); }
        }
        for (; k + 4 <= n; k += 4) {
            unsigned int u[4];
#pragma unroll
            for (int q = 0; q < 4; q++) {
                int s = __shfl(myidx, k + q);
                u[q] = ts[s * 64 + lane];
            }
#pragma unroll
            for (int q = 0; q < 4; q++) { ax += bflo(u[q]); ay += bfhi(u[q]); }
        }
        for (; k < n; k++) {
            int s = __shfl(myidx, k);
            unsigned int u = ts[s * 64 + lane];
            ax += bflo(u); ay += bfhi(u);
        }
    }
    unsigned int su = ts[(size_t)node * 64 + lane];  // self-loop (pre-scaled)
    float bx = bias[lane * 2 + 0], by = bias[lane * 2 + 1];
    float ox = fmaxf(fmaf(di, ax + bflo(su), bx), 0.f);
    float oy = fmaxf(fmaf(di, ay + bfhi(su), by), 0.f);
    out[(size_t)node * 64 + lane] = f2bf(ox) | (f2bf(oy) << 16);
}

// ------------- mean pool per graph (batch sorted), bf16 h input -------------
__global__ __launch_bounds__(256) void k_pool(const unsigned int* __restrict__ h,
                                              const int* __restrict__ batch,
                                              float* __restrict__ pooled) {
    int g = blockIdx.x;
    int t = threadIdx.x;
    int f = t & 63, part = t >> 6;  // f: uint col, part: 4-way row split
    int lo = 0, hi = GN;
    while (lo < hi) { int m = (lo + hi) >> 1; if (batch[m] < g) lo = m + 1; else hi = m; }
    int start = lo;
    hi = GN;
    while (lo < hi) { int m = (lo + hi) >> 1; if (batch[m] <= g) lo = m + 1; else hi = m; }
    int end = lo;
    float ax = 0.f, ay = 0.f;
    for (int i = start + part; i < end; i += 4) {
        unsigned int u = h[(size_t)i * 64 + f];
        ax += bflo(u); ay += bfhi(u);
    }
    __shared__ float redx[256], redy[256];
    redx[t] = ax; redy[t] = ay;
    __syncthreads();
    if (part == 0) {
        float sx = redx[f] + redx[f + 64] + redx[f + 128] + redx[f + 192];
        float sy = redy[f] + redy[f + 64] + redy[f + 128] + redy[f + 192];
        float inv = 1.0f / fmaxf((float)(end - start), 1.0f);
        pooled[g * 128 + 2 * f + 0] = sx * inv;
        pooled[g * 128 + 2 * f + 1] = sy * inv;
    }
}

// ------------- value head -------------
__global__ void k_value(const float* __restrict__ pooled, const float* __restrict__ Wv,
                        const float* __restrict__ bv, float* __restrict__ out) {
    int g = threadIdx.x;
    const float4* p4 = (const float4*)(pooled + g * 128);
    const float4* w4 = (const float4*)Wv;
    float s = 0.f;
#pragma unroll 8
    for (int i = 0; i < 32; i++) {
        float4 a = p4[i], b = w4[i];
        s += a.x * b.x + a.y * b.y + a.z * b.z + a.w * b.w;
    }
    out[g] = tanhf(s + bv[0]);
}

// ------------- policy head: 4 graphs/block (Wp read amortized 4x) -------------
__global__ __launch_bounds__(256) void k_policy(const float* __restrict__ pooled,
                                                const float* __restrict__ Wp,
                                                const float* __restrict__ bp,
                                                float* __restrict__ out) {
    int g0 = blockIdx.x * 4;
    int t = threadIdx.x;
    __shared__ float pr[4][128];
    __shared__ float red[256];
    if (t < 128) {
#pragma unroll
        for (int gg = 0; gg < 4; gg++)
            pr[gg][t] = pooled[(size_t)(g0 + gg) * 128 + t];
    }
    __syncthreads();
    float bb0 = bp[t], bb1 = bp[t + 256], bb2 = bp[t + 512], bb3 = bp[t + 768];
    float acc[4][4];
#pragma unroll
    for (int gg = 0; gg < 4; gg++) {
        acc[gg][0] = bb0; acc[gg][1] = bb1; acc[gg][2] = bb2; acc[gg][3] = bb3;
    }
    for (int k = 0; k < 128; k++) {
        const float* wr = Wp + (size_t)k * 1024;
        float w0 = wr[t], w1 = wr[t + 256], w2 = wr[t + 512], w3 = wr[t + 768];
#pragma unroll
        for (int gg = 0; gg < 4; gg++) {
            float pv = pr[gg][k];
            acc[gg][0] = fmaf(pv, w0, acc[gg][0]);
            acc[gg][1] = fmaf(pv, w1, acc[gg][1]);
            acc[gg][2] = fmaf(pv, w2, acc[gg][2]);
            acc[gg][3] = fmaf(pv, w3, acc[gg][3]);
        }
    }
#pragma unroll
    for (int gg = 0; gg < 4; gg++) {
        float m = fmaxf(fmaxf(acc[gg][0], acc[gg][1]), fmaxf(acc[gg][2], acc[gg][3]));
        red[t] = m;
        __syncthreads();
        for (int off = 128; off > 0; off >>= 1) {
            if (t < off) red[t] = fmaxf(red[t], red[t + off]);
            __syncthreads();
        }
        float mx = red[0];
        __syncthreads();
        float e0 = __expf(acc[gg][0] - mx), e1 = __expf(acc[gg][1] - mx);
        float e2 = __expf(acc[gg][2] - mx), e3 = __expf(acc[gg][3] - mx);
        red[t] = (e0 + e1) + (e2 + e3);
        __syncthreads();
        for (int off = 128; off > 0; off >>= 1) {
            if (t < off) red[t] += red[t + off];
            __syncthreads();
        }
        float inv = 1.0f / red[0];
        __syncthreads();
        size_t ob = (size_t)(g0 + gg) * 1024;
        out[ob + t + 0]   = e0 * inv;
        out[ob + t + 256] = e1 * inv;
        out[ob + t + 512] = e2 * inv;
        out[ob + t + 768] = e3 * inv;
    }
}

extern "C" void kernel_launch(void* const* d_in, const int* in_sizes, int n_in,
                              void* d_out, int out_size, void* d_ws, size_t ws_size,
                              hipStream_t stream) {
    const float* x    = (const float*)d_in[0];
    const int*   ei   = (const int*)d_in[1];
    const int*   srcA = ei;        // edge_index[0]
    const int*   dstA = ei + GE;   // edge_index[1]
    const int*   batch = (const int*)d_in[2];
    const float* W1 = (const float*)d_in[3];
    const float* b1 = (const float*)d_in[4];
    const float* W2 = (const float*)d_in[5];
    const float* b2 = (const float*)d_in[6];
    const float* Wv = (const float*)d_in[7];
    const float* bv = (const float*)d_in[8];
    const float* Wp = (const float*)d_in[9];
    const float* bp = (const float*)d_in[10];
    float* out = (float*)d_out;

    char* ws = (char*)d_ws;
    unsigned int* bufH = (unsigned int*)ws;  ws += (size_t)GN * 64 * 4;      // 25.6 MB bf16 h
    unsigned int* ts_bf = (unsigned int*)ws; ws += (size_t)GN * 64 * 4;      // 25.6 MB bf16 ts
    float* pooled = (float*)ws;      ws += (size_t)GB * 128 * 4;
    float* dinv = (float*)ws;        ws += (size_t)100352 * 4;
    int*   nbeg = (int*)ws;          ws += (size_t)100352 * 4;
    int*   nend = (int*)ws;          ws += (size_t)100352 * 4;
    int*   csr_src = (int*)ws;       ws += (size_t)NBUK * BCAP * 4;          // 19.2 MB padded
    int*   gcur = (int*)ws;          ws += 512 * 4;
    unsigned short* Wsw1 = (unsigned short*)ws; ws += 16384 * 2;
    unsigned short* Wsw2 = (unsigned short*)ws; ws += 16384 * 2;
    unsigned int* binned = ts_bf;    // alias (19.2 MB < 25.6 MB): consumed by k_sort2
                                     // before k_gemm1 writes ts

    // --- prep (W swizzle + cursor init) + CSR build ---
    k_prep<<<129, 256, 0, stream>>>(W1, W2, Wsw1, Wsw2, gcur);
    k_bin1<<<NBIN1, 256, 0, stream>>>(srcA, dstA, gcur, binned);
    k_sort2<<<NBUK, 256, 0, stream>>>(binned, gcur, csr_src, nbeg, nend, dinv);

    // --- layer 1: ts = bf16(dinv .* (x @ W1)); h1 = relu(dinv*(gather + self) + b1) ---
    k_gemm1<<<(GN + 63) / 64, 256, 0, stream>>>(x, Wsw1, dinv, ts_bf);
    k_aggregate<<<GN / 4, 256, 0, stream>>>(ts_bf, nbeg, nend, csr_src, dinv, b1, bufH);

    // --- layer 2 ---
    k_gemm2<<<(GN + 63) / 64, 256, 0, stream>>>(bufH, Wsw2, dinv, ts_bf);
    k_aggregate<<<GN / 4, 256, 0, stream>>>(ts_bf, nbeg, nend, csr_src, dinv, b2, bufH);

    // --- pool + heads ---
    k_pool<<<GB, 256, 0, stream>>>(bufH, batch, pooled);
    k_value<<<1, 256, 0, stream>>>(pooled, Wv, bv, out);
    k_policy<<<GB / 4, 256, 0, stream>>>(pooled, Wp, bp, out + GB);
}